// Round 7
// baseline (197.533 us; speedup 1.0000x reference)
//
#include <hip/hip_runtime.h>
#include <hip/hip_bf16.h>

#define NN   4096   // nodes
#define DD   512    // in_dim (= 8 heads * 64)
#define KH   8      // heads
#define RR   64     // sub_dim
#define CAP  128    // max neighbors kept (deg ~ 42 +- 6.4; 128 is 13 sigma)

typedef unsigned short u16;
typedef unsigned int   u32;
typedef __attribute__((ext_vector_type(8))) short short8;  // 8 bf16 (MFMA A/B frag)
typedef __attribute__((ext_vector_type(4))) float f32x4;   // MFMA C/D frag

__device__ __forceinline__ float bflo(u32 v){ union{u32 i; float f;} c; c.i = v << 16;        return c.f; }
__device__ __forceinline__ float bfhi(u32 v){ union{u32 i; float f;} c; c.i = v & 0xFFFF0000u; return c.f; }
__device__ __forceinline__ u16 f2bf(float f){ __hip_bfloat16 h = __float2bfloat16(f); return *reinterpret_cast<u16*>(&h); }

// ---------------------------------------------------------------------------
// P0 (merged prep): b<2048: H->Hb bf16. b<2112: U -> Bt1/Bt2 bf16 transposes.
// b==2112: zero loss/done scalars.
// ---------------------------------------------------------------------------
__global__ __launch_bounds__(256) void prep_all(const float* __restrict__ H, const float* __restrict__ U,
                                                u16* __restrict__ Hb, u16* __restrict__ Bt1,
                                                u16* __restrict__ Bt2, float* __restrict__ lossA,
                                                int* __restrict__ doneA) {
    __shared__ float tile[64][65];
    int b = blockIdx.x, t = threadIdx.x;
    if (b < 2048) {
        size_t id = (size_t)b * 256 + t;
        float4 v = *(const float4*)(H + id * 4);
        ushort4 o; o.x = f2bf(v.x); o.y = f2bf(v.y); o.z = f2bf(v.z); o.w = f2bf(v.w);
        *(ushort4*)(Hb + id * 4) = o;
        return;
    }
    if (b == 2112) { if (t == 0) { lossA[0] = 0.f; doneA[0] = 0; } return; }
    int b2 = b - 2048;
    int k = b2 >> 3, d0 = (b2 & 7) * 64;
    #pragma unroll
    for (int s = 0; s < 4; s++) {
        int u = t + 256 * s;               // 0..1023
        int dd = u >> 4, rq = u & 15;
        float4 v = *(const float4*)(U + ((size_t)(k * DD + d0 + dd)) * RR + rq * 4);
        tile[dd][rq * 4 + 0] = v.x; tile[dd][rq * 4 + 1] = v.y;
        tile[dd][rq * 4 + 2] = v.z; tile[dd][rq * 4 + 3] = v.w;
    }
    __syncthreads();
    {   // Bt1[k*64+r][d0+dd]
        int r = t >> 2;
        #pragma unroll
        for (int ii = 0; ii < 16; ii++) {
            int dd = (t & 3) * 16 + ii;
            Bt1[(size_t)(k * RR + r) * DD + d0 + dd] = f2bf(tile[dd][r]);
        }
    }
    {   // Bt2[d0+dd][k*64+r]
        int dd = t >> 2, rb = (t & 3) * 16;
        #pragma unroll
        for (int ii = 0; ii < 16; ii++) {
            Bt2[(size_t)(d0 + dd) * DD + k * RR + rb + ii] = f2bf(tile[dd][rb + ii]);
        }
    }
}

// ---------------------------------------------------------------------------
// MID: one kernel, three independent jobs running concurrently:
//   b <  4096 : mask scan -> nlist/cnt (HBM-streaming)
//   b <  4608 : zgemm  Zb = Hb . Bt1^T (bf16 MFMA, 64x64 tile)
//   b <  4720 : orth loss (LLC reads + VALU), done-counter writes loss to out
// ---------------------------------------------------------------------------
struct GemmSh { short As[64][72]; short Bs[64][72]; };
struct OrthSh { float UkT[64][20]; float UlT[64][68]; float red[4]; };
struct ScanSh { int cnt; };
union  MidSh  { GemmSh g; OrthSh o; ScanSh s; };

__global__ __launch_bounds__(256) void mid_kernel(const u16* __restrict__ Hb, const u16* __restrict__ Bt1,
                                                  u16* __restrict__ Zb,
                                                  const float* __restrict__ adj, int* __restrict__ nlist,
                                                  int* __restrict__ cnt,
                                                  const float* __restrict__ U, float* __restrict__ loss,
                                                  int* __restrict__ done, float* __restrict__ outLoss) {
    __shared__ MidSh sh;
    const int b = blockIdx.x, t = threadIdx.x;
    if (b < 4096) {
        // ---- mask scan ----
        const int i = b;
        if (t == 0) sh.s.cnt = 0;
        __syncthreads();
        const float* arow = adj + (size_t)i * NN;
        #pragma unroll
        for (int qq = 0; qq < 4; qq++) {
            int j = (qq * 256 + t) * 4;
            float4 mv = *(const float4*)(arow + j);
            if (mv.x != 0.f) { int p = atomicAdd(&sh.s.cnt, 1); if (p < CAP) nlist[(size_t)i * CAP + p] = j;     }
            if (mv.y != 0.f) { int p = atomicAdd(&sh.s.cnt, 1); if (p < CAP) nlist[(size_t)i * CAP + p] = j + 1; }
            if (mv.z != 0.f) { int p = atomicAdd(&sh.s.cnt, 1); if (p < CAP) nlist[(size_t)i * CAP + p] = j + 2; }
            if (mv.w != 0.f) { int p = atomicAdd(&sh.s.cnt, 1); if (p < CAP) nlist[(size_t)i * CAP + p] = j + 3; }
        }
        __syncthreads();
        if (t == 0) cnt[i] = min(sh.s.cnt, CAP);
        return;
    }
    if (b < 4608) {
        // ---- zgemm: Zb[n][c] = Hb[n][:] . Bt1[c][:] ----
        const int bb = b - 4096;
        const int i0 = (bb & 63) * 64, n0 = (bb >> 6) * 64;
        const int w = t >> 6, lane = t & 63;
        const int lm = lane & 15, lg = lane >> 4;
        f32x4 acc[4] = {};
        for (int kc = 0; kc < DD; kc += 64) {
            #pragma unroll
            for (int s = 0; s < 2; s++) {
                int c = t + 256 * s; int row = c >> 3, g = c & 7;
                *(short8*)&sh.g.As[row][g * 8] = *(const short8*)(Hb  + (size_t)(i0 + row) * DD + kc + g * 8);
                *(short8*)&sh.g.Bs[row][g * 8] = *(const short8*)(Bt1 + (size_t)(n0 + row) * DD + kc + g * 8);
            }
            __syncthreads();
            #pragma unroll
            for (int ks = 0; ks < 64; ks += 32) {
                short8 af = *(const short8*)&sh.g.As[w * 16 + lm][ks + lg * 8];
                #pragma unroll
                for (int bq = 0; bq < 4; bq++) {
                    short8 bfr = *(const short8*)&sh.g.Bs[bq * 16 + lm][ks + lg * 8];
                    acc[bq] = __builtin_amdgcn_mfma_f32_16x16x32_bf16(af, bfr, acc[bq], 0, 0, 0);
                }
            }
            __syncthreads();
        }
        // C/D: col = lane&15, row = (lane>>4)*4 + reg  [m89-verified]
        #pragma unroll
        for (int bq = 0; bq < 4; bq++)
            #pragma unroll
            for (int q = 0; q < 4; q++) {
                int row = i0 + w * 16 + lg * 4 + q;
                int col = n0 + bq * 16 + lm;
                Zb[(size_t)row * DD + col] = f2bf(acc[bq][q]);
            }
        return;
    }
    // ---- orth loss ----
    const int ob = b - 4608;
    const int pb = ob >> 2, strip = ob & 3;
    int idx = pb, k = 0, lh = 1;
    #pragma unroll
    for (int kk = 0; kk < 8; kk++) {
        int c = 7 - kk;
        if (idx < c) { k = kk; lh = kk + 1 + idx; break; }
        idx -= c;
    }
    const int r = t & 15;
    const int s0 = (t >> 4) * 4;
    const int r0g = strip * 16;
    const float* Uk = U + (size_t)k  * DD * RR;
    const float* Ul = U + (size_t)lh * DD * RR;
    float a0 = 0.f, a1 = 0.f, a2 = 0.f, a3 = 0.f;
    for (int dc = 0; dc < DD; dc += 64) {
        {   int dd = t >> 2, rq = t & 3;
            *(float4*)&sh.o.UkT[dd][rq * 4] = *(const float4*)(Uk + (size_t)(dc + dd) * RR + r0g + rq * 4);
        }
        #pragma unroll
        for (int s = 0; s < 4; s++) {
            int u = t + 256 * s;
            int dd = u >> 4, sq = u & 15;
            *(float4*)&sh.o.UlT[dd][sq * 4] = *(const float4*)(Ul + (size_t)(dc + dd) * RR + sq * 4);
        }
        __syncthreads();
        #pragma unroll 4
        for (int dd = 0; dd < 64; dd++) {
            float a = sh.o.UkT[dd][r];
            float4 bv = *(const float4*)&sh.o.UlT[dd][s0];
            a0 += a * bv.x; a1 += a * bv.y; a2 += a * bv.z; a3 += a * bv.w;
        }
        __syncthreads();
    }
    float v = a0 * a0 + a1 * a1 + a2 * a2 + a3 * a3;
    #pragma unroll
    for (int off = 32; off; off >>= 1) v += __shfl_down(v, off, 64);
    if ((t & 63) == 0) sh.o.red[t >> 6] = v;
    __syncthreads();
    if (t == 0) {
        atomicAdd(loss, sh.o.red[0] + sh.o.red[1] + sh.o.red[2] + sh.o.red[3]);
        __threadfence();
        int d = atomicAdd(done, 1);
        if (d == 111) {
            float total = atomicAdd(loss, 0.f);   // device-coherent read of final sum
            outLoss[0] = total;
        }
    }
}

// ---------------------------------------------------------------------------
// K2: sparse attention from nlist. Block (512 thr) per row, wave=head.
// Chunk 16, quad gather (4 lanes/neighbor, 16 dims each), stage to per-wave
// LDS (u32), online softmax via xor-butterflies, agg from LDS (2 dims/lane,
// even/odd-c half-waves). wave_barrier() fences stage-write->agg-read and
// agg-read->next-write (same-wave LDS ordering; HW is in-order per wave).
// Bit-equiv to dense masked softmax (-1e9 scores underflow to exp=0 in f32).
// ---------------------------------------------------------------------------
__global__ __launch_bounds__(512) void attn6(const u16* __restrict__ Zb, const int* __restrict__ nlist,
                                             const int* __restrict__ cnt, u16* __restrict__ Zaggb) {
    const int i = blockIdx.x, t = threadIdx.x;
    const int k = t >> 6, lane = t & 63;
    __shared__ int   nbrS[CAP + 16];     // padded with nbrS[0]: chunk tails need no guards
    __shared__ float ziS[DD];
    __shared__ u32   zbufU[KH][16][36];  // [wave][nbr][32 u32 = 64 dims], 144 B rows
    const int ci = cnt[i];               // >= 1 (self-loop)
    for (int u = t; u < ci; u += 512) nbrS[u] = nlist[(size_t)i * CAP + u];
    if (t < 256) {
        u32 v = *(const u32*)(Zb + (size_t)i * DD + t * 2);
        ziS[t * 2] = bflo(v); ziS[t * 2 + 1] = bfhi(v);
    }
    __syncthreads();
    if (t < 16) nbrS[ci + t] = nbrS[0];
    __syncthreads();

    const int n = lane >> 2, q = lane & 3;      // score roles: neighbor slot, dim-quarter
    const int half = lane >> 5, L = lane & 31;  // agg roles: c-parity, dim pair
    const float4* zi4 = (const float4*)(ziS + k * 64 + q * 16);
    float m = -3.0e38f, l = 0.f, accA = 0.f, accB = 0.f;

    for (int base = 0; base < ci; base += 16) {
        const int cact = min(16, ci - base);
        const int j = nbrS[base + n];           // padded: safe for n >= cact
        __builtin_amdgcn_wave_barrier();        // WAR: prior agg reads before this chunk's writes
        // --- gather 16 dims (32 B, 2 indep 16B loads), stage, dot ---
        const uint4* zp = (const uint4*)(Zb + (size_t)j * DD + k * 64 + q * 16);
        uint4 v0 = zp[0], v1 = zp[1];
        *(uint4*)&zbufU[k][n][q * 8]     = v0;
        *(uint4*)&zbufU[k][n][q * 8 + 4] = v1;
        float4 a0 = zi4[0], a1 = zi4[1], a2 = zi4[2], a3 = zi4[3];
        float s = bflo(v0.x)*a0.x + bfhi(v0.x)*a0.y + bflo(v0.y)*a0.z + bfhi(v0.y)*a0.w
                + bflo(v0.z)*a1.x + bfhi(v0.z)*a1.y + bflo(v0.w)*a1.z + bfhi(v0.w)*a1.w
                + bflo(v1.x)*a2.x + bfhi(v1.x)*a2.y + bflo(v1.y)*a2.z + bfhi(v1.y)*a2.w
                + bflo(v1.z)*a3.x + bfhi(v1.z)*a3.y + bflo(v1.w)*a3.z + bfhi(v1.w)*a3.w;
        s += __shfl_xor(s, 1);
        s += __shfl_xor(s, 2);                  // all 4 quad lanes hold the full dot
        s *= 0.125f;                            // 1/sqrt(64)
        if (n >= cact) s = -3.0e38f;
        // --- online softmax: quad-uniform values, butterfly over groups ---
        float mx = s;
        #pragma unroll
        for (int off = 4; off < 64; off <<= 1) mx = fmaxf(mx, __shfl_xor(mx, off));
        const float mnew = fmaxf(m, mx);
        const float scale = __expf(m - mnew);
        const float e = (n < cact) ? __expf(s - mnew) : 0.f;
        float se = e;                           // quad-uniform: group butterfly sums each nbr once
        #pragma unroll
        for (int off = 4; off < 64; off <<= 1) se += __shfl_xor(se, off);
        l = l * scale + se;
        m = mnew;
        accA *= scale; accB *= scale;
        __builtin_amdgcn_wave_barrier();        // RAW: stage writes before agg reads
        // --- aggregation from LDS: half-wave on c-parity, 2 dims/lane (u32) ---
        for (int c = half; c < cact; c += 2) {
            const float wgt = __shfl(e, 4 * c); // neighbor c's weight (lane 4c)
            u32 z2 = zbufU[k][c][L];
            accA += wgt * bflo(z2);
            accB += wgt * bfhi(z2);
        }
    }
    accA += __shfl_xor(accA, 32);               // combine even/odd-c halves
    accB += __shfl_xor(accB, 32);
    if (lane < 32) {
        const float inv = 1.0f / l;
        u32 o = ((u32)f2bf(accA * inv)) | (((u32)f2bf(accB * inv)) << 16);
        *(u32*)(Zaggb + (size_t)i * DD + k * 64 + 2 * L) = o;
    }
}

// ---------------------------------------------------------------------------
// K3: out = relu(H + 0.5 * (Zaggb . Bt2^T) - thr), f32 out. 64x64, BK=64.
// ---------------------------------------------------------------------------
__global__ __launch_bounds__(256) void outgemm_mfma(const u16* __restrict__ Ab, const u16* __restrict__ Btb,
                                                    const float* __restrict__ H, const float* __restrict__ thr,
                                                    float* __restrict__ out) {
    __shared__ short As[64][72];
    __shared__ short Bs[64][72];
    const int t = threadIdx.x;
    const int i0 = blockIdx.x * 64, n0 = blockIdx.y * 64;
    const int w = t >> 6, lane = t & 63;
    const int lm = lane & 15, lg = lane >> 4;
    f32x4 acc[4] = {};
    for (int kc = 0; kc < DD; kc += 64) {
        #pragma unroll
        for (int s = 0; s < 2; s++) {
            int c = t + 256 * s; int row = c >> 3, g = c & 7;
            *(short8*)&As[row][g * 8] = *(const short8*)(Ab  + (size_t)(i0 + row) * DD + kc + g * 8);
            *(short8*)&Bs[row][g * 8] = *(const short8*)(Btb + (size_t)(n0 + row) * DD + kc + g * 8);
        }
        __syncthreads();
        #pragma unroll
        for (int ks = 0; ks < 64; ks += 32) {
            short8 af = *(const short8*)&As[w * 16 + lm][ks + lg * 8];
            #pragma unroll
            for (int b = 0; b < 4; b++) {
                short8 bfr = *(const short8*)&Bs[b * 16 + lm][ks + lg * 8];
                acc[b] = __builtin_amdgcn_mfma_f32_16x16x32_bf16(af, bfr, acc[b], 0, 0, 0);
            }
        }
        __syncthreads();
    }
    #pragma unroll
    for (int b = 0; b < 4; b++) {
        const int col = n0 + b * 16 + lm;
        const float th = thr[col];
        #pragma unroll
        for (int q = 0; q < 4; q++) {
            int row = i0 + w * 16 + lg * 4 + q;
            float h = H[(size_t)row * DD + col];
            out[(size_t)row * DD + col] = fmaxf(h + 0.5f * acc[b][q] - th, 0.f);
        }
    }
}

// ---------------------------------------------------------------------------
extern "C" void kernel_launch(void* const* d_in, const int* in_sizes, int n_in,
                              void* d_out, int out_size, void* d_ws, size_t ws_size,
                              hipStream_t stream) {
    const float* H   = (const float*)d_in[0];
    const float* adj = (const float*)d_in[1];
    const float* U   = (const float*)d_in[2];
    const float* thr = (const float*)d_in[3];
    float* out = (float*)d_out;

    char* ws = (char*)d_ws;
    float* lossA = (float*)ws;                                         // 4 B
    int*   doneA = (int*)(ws + 64);                                    // 4 B
    u16*   Hb    = (u16*)(ws + 1024);                                  // 4 MB
    u16*   Zb    = (u16*)(ws + 1024 + 4u * 1024 * 1024);               // 4 MB
    u16*   Zaggb = (u16*)(ws + 1024 + 8u * 1024 * 1024);               // 4 MB
    u16*   Bt1   = (u16*)(ws + 1024 + 12u * 1024 * 1024);              // 512 KB
    u16*   Bt2   = (u16*)(ws + 1024 + 12u * 1024 * 1024 + 512u * 1024);// 512 KB
    int*   nlist = (int*)(ws + 1024 + 13u * 1024 * 1024);              // 2 MB
    int*   cnt   = (int*)(ws + 1024 + 15u * 1024 * 1024 + 512u * 1024);// 16 KB

    prep_all<<<2113, 256, 0, stream>>>(H, U, Hb, Bt1, Bt2, lossA, doneA);
    mid_kernel<<<4720, 256, 0, stream>>>(Hb, Bt1, Zb, adj, nlist, cnt,
                                         U, lossA, doneA, out + (size_t)NN * DD);
    attn6<<<NN, 512, 0, stream>>>(Zb, nlist, cnt, Zaggb);
    outgemm_mfma<<<dim3(64, 8), 256, 0, stream>>>(Zaggb, Bt2, H, thr, out);
}

// Round 8
// 173.567 us; speedup vs baseline: 1.1381x; 1.1381x over previous
//
#include <hip/hip_runtime.h>
#include <hip/hip_bf16.h>

#define NN   4096   // nodes
#define DD   512    // in_dim (= 8 heads * 64)
#define KH   8      // heads
#define RR   64     // sub_dim
#define CAP  128    // max neighbors kept (deg ~ 42 +- 6.4; 128 is 13 sigma)

typedef unsigned short u16;
typedef unsigned int   u32;
typedef __attribute__((ext_vector_type(8))) short short8;  // 8 bf16 (MFMA A/B frag)
typedef __attribute__((ext_vector_type(4))) float f32x4;   // MFMA C/D frag

__device__ __forceinline__ float bflo(u32 v){ union{u32 i; float f;} c; c.i = v << 16;        return c.f; }
__device__ __forceinline__ float bfhi(u32 v){ union{u32 i; float f;} c; c.i = v & 0xFFFF0000u; return c.f; }
__device__ __forceinline__ u16 f2bf(float f){ __hip_bfloat16 h = __float2bfloat16(f); return *reinterpret_cast<u16*>(&h); }

// ---------------------------------------------------------------------------
// P0: streaming prep. b<4096: mask scan -> nlist/cnt (LDS compaction, coalesced
// copy-out). b<6144: H->Hb bf16. b<6208: U -> Bt1/Bt2 transposes. b=6208: zero
// scalars. All jobs are HBM-streaming / VALU-light; no MFMA contention.
// ---------------------------------------------------------------------------
__global__ __launch_bounds__(256) void prep_scan(const float* __restrict__ H, const float* __restrict__ U,
                                                 const float* __restrict__ adj,
                                                 u16* __restrict__ Hb, u16* __restrict__ Bt1,
                                                 u16* __restrict__ Bt2,
                                                 int* __restrict__ nlist, int* __restrict__ cnt,
                                                 float* __restrict__ lossA, int* __restrict__ doneA) {
    __shared__ float tile[64][65];
    __shared__ int   list[CAP];
    __shared__ int   cntS;
    const int b = blockIdx.x, t = threadIdx.x;
    if (b < 4096) {
        // ---- mask scan ----
        const int i = b;
        if (t == 0) cntS = 0;
        __syncthreads();
        const float* arow = adj + (size_t)i * NN;
        #pragma unroll
        for (int qq = 0; qq < 4; qq++) {
            int j = (qq * 256 + t) * 4;
            float4 mv = *(const float4*)(arow + j);
            if (mv.x != 0.f) { int p = atomicAdd(&cntS, 1); if (p < CAP) list[p] = j;     }
            if (mv.y != 0.f) { int p = atomicAdd(&cntS, 1); if (p < CAP) list[p] = j + 1; }
            if (mv.z != 0.f) { int p = atomicAdd(&cntS, 1); if (p < CAP) list[p] = j + 2; }
            if (mv.w != 0.f) { int p = atomicAdd(&cntS, 1); if (p < CAP) list[p] = j + 3; }
        }
        __syncthreads();
        const int n = min(cntS, CAP);
        if (t < n) nlist[(size_t)i * CAP + t] = list[t];
        if (t == 0) cnt[i] = n;
        return;
    }
    if (b < 6144) {
        // ---- H (f32) -> Hb (bf16) ----
        size_t id = (size_t)(b - 4096) * 256 + t;
        float4 v = *(const float4*)(H + id * 4);
        ushort4 o; o.x = f2bf(v.x); o.y = f2bf(v.y); o.z = f2bf(v.z); o.w = f2bf(v.w);
        *(ushort4*)(Hb + id * 4) = o;
        return;
    }
    if (b == 6208) { if (t == 0) { lossA[0] = 0.f; doneA[0] = 0; } return; }
    // ---- U -> Bt1 [k*64+r][d], Bt2 [d][k*64+r] (bf16) ----
    const int b2 = b - 6144;
    const int k = b2 >> 3, d0 = (b2 & 7) * 64;
    #pragma unroll
    for (int s = 0; s < 4; s++) {
        int u = t + 256 * s;               // 0..1023
        int dd = u >> 4, rq = u & 15;
        float4 v = *(const float4*)(U + ((size_t)(k * DD + d0 + dd)) * RR + rq * 4);
        tile[dd][rq * 4 + 0] = v.x; tile[dd][rq * 4 + 1] = v.y;
        tile[dd][rq * 4 + 2] = v.z; tile[dd][rq * 4 + 3] = v.w;
    }
    __syncthreads();
    {   int r = t >> 2;
        #pragma unroll
        for (int ii = 0; ii < 16; ii++) {
            int dd = (t & 3) * 16 + ii;
            Bt1[(size_t)(k * RR + r) * DD + d0 + dd] = f2bf(tile[dd][r]);
        }
    }
    {   int dd = t >> 2, rb = (t & 3) * 16;
        #pragma unroll
        for (int ii = 0; ii < 16; ii++) {
            Bt2[(size_t)(d0 + dd) * DD + k * RR + rb + ii] = f2bf(tile[dd][rb + ii]);
        }
    }
}

// ---------------------------------------------------------------------------
// K1: Zb[n][c=k*64+r] = Hb[n][:] . Bt1[c][:]  (bf16 MFMA) 64x64 tile, BK=64.
// ---------------------------------------------------------------------------
__global__ __launch_bounds__(256) void zgemm_mfma(const u16* __restrict__ Hb, const u16* __restrict__ Bt1,
                                                  u16* __restrict__ Zb) {
    __shared__ short As[64][72];   // 144 B rows, 16B-aligned
    __shared__ short Bs[64][72];
    const int t = threadIdx.x;
    const int i0 = blockIdx.x * 64, n0 = blockIdx.y * 64;
    const int w = t >> 6, lane = t & 63;
    const int lm = lane & 15, lg = lane >> 4;
    f32x4 acc[4] = {};
    for (int kc = 0; kc < DD; kc += 64) {
        #pragma unroll
        for (int s = 0; s < 2; s++) {
            int c = t + 256 * s; int row = c >> 3, g = c & 7;
            *(short8*)&As[row][g * 8] = *(const short8*)(Hb  + (size_t)(i0 + row) * DD + kc + g * 8);
            *(short8*)&Bs[row][g * 8] = *(const short8*)(Bt1 + (size_t)(n0 + row) * DD + kc + g * 8);
        }
        __syncthreads();
        #pragma unroll
        for (int ks = 0; ks < 64; ks += 32) {
            short8 af = *(const short8*)&As[w * 16 + lm][ks + lg * 8];
            #pragma unroll
            for (int b = 0; b < 4; b++) {
                short8 bfr = *(const short8*)&Bs[b * 16 + lm][ks + lg * 8];
                acc[b] = __builtin_amdgcn_mfma_f32_16x16x32_bf16(af, bfr, acc[b], 0, 0, 0);
            }
        }
        __syncthreads();
    }
    // C/D: col = lane&15, row = (lane>>4)*4 + reg  [m89-verified]
    #pragma unroll
    for (int b = 0; b < 4; b++)
        #pragma unroll
        for (int q = 0; q < 4; q++) {
            int row = i0 + w * 16 + lg * 4 + q;
            int col = n0 + b * 16 + lm;
            Zb[(size_t)row * DD + col] = f2bf(acc[b][q]);
        }
}

// ---------------------------------------------------------------------------
// K2: sparse attention from nlist. Block (512 thr) per row, wave=head.
// Chunk 16, quad gather (4 lanes/neighbor, 16 dims), stage to per-wave LDS;
// online softmax via xor-butterflies; weights through LDS wS; aggregation
// reads packed u32 (2 dims/lane, even/odd-c half-waves). __syncthreads()
// between stage-write and agg-read (and before next chunk's overwrite):
// same ordering attn3 validated at absmax 0.03 — wave_barrier alone is NOT
// a memory fence (round 6/7 absmax 2.4/2.6).
// Bit-equiv to dense masked softmax (-1e9 scores underflow to exp=0 in f32).
// ---------------------------------------------------------------------------
__global__ __launch_bounds__(512) void attn7(const u16* __restrict__ Zb, const int* __restrict__ nlist,
                                             const int* __restrict__ cnt, u16* __restrict__ Zaggb) {
    const int i = blockIdx.x, t = threadIdx.x;
    const int k = t >> 6, lane = t & 63;
    __shared__ int   nbrS[CAP + 16];     // padded with nbrS[0]: chunk tails need no guards
    __shared__ float ziS[DD];
    __shared__ u32   zbufU[KH][16][36];  // [wave][nbr][32 u32 = 64 dims], 144 B rows
    __shared__ float wS[KH][16];
    const int ci = cnt[i];               // >= 1 (self-loop)
    for (int u = t; u < ci; u += 512) nbrS[u] = nlist[(size_t)i * CAP + u];
    if (t < 256) {
        u32 v = *(const u32*)(Zb + (size_t)i * DD + t * 2);
        ziS[t * 2] = bflo(v); ziS[t * 2 + 1] = bfhi(v);
    }
    __syncthreads();
    if (t < 16) nbrS[ci + t] = nbrS[0];
    __syncthreads();

    const int n = lane >> 2, q = lane & 3;      // score roles: neighbor slot, dim-quarter
    const int half = lane >> 5, L = lane & 31;  // agg roles: c-parity, dim pair
    const float4* zi4 = (const float4*)(ziS + k * 64 + q * 16);
    float m = -3.0e38f, l = 0.f, accA = 0.f, accB = 0.f;

    for (int base = 0; base < ci; base += 16) {
        const int cact = min(16, ci - base);
        const int j = nbrS[base + n];           // padded: safe for n >= cact
        // --- gather 16 dims (32 B, 2 indep 16B loads), stage, dot ---
        const uint4* zp = (const uint4*)(Zb + (size_t)j * DD + k * 64 + q * 16);
        uint4 v0 = zp[0], v1 = zp[1];
        *(uint4*)&zbufU[k][n][q * 8]     = v0;
        *(uint4*)&zbufU[k][n][q * 8 + 4] = v1;
        float4 a0 = zi4[0], a1 = zi4[1], a2 = zi4[2], a3 = zi4[3];
        float s = bflo(v0.x)*a0.x + bfhi(v0.x)*a0.y + bflo(v0.y)*a0.z + bfhi(v0.y)*a0.w
                + bflo(v0.z)*a1.x + bfhi(v0.z)*a1.y + bflo(v0.w)*a1.z + bfhi(v0.w)*a1.w
                + bflo(v1.x)*a2.x + bfhi(v1.x)*a2.y + bflo(v1.y)*a2.z + bfhi(v1.y)*a2.w
                + bflo(v1.z)*a3.x + bfhi(v1.z)*a3.y + bflo(v1.w)*a3.z + bfhi(v1.w)*a3.w;
        s += __shfl_xor(s, 1);
        s += __shfl_xor(s, 2);                  // all 4 quad lanes hold the full dot
        s *= 0.125f;                            // 1/sqrt(64)
        if (n >= cact) s = -3.0e38f;
        // --- online softmax: quad-uniform values, butterfly over groups ---
        float mx = s;
        #pragma unroll
        for (int off = 4; off < 64; off <<= 1) mx = fmaxf(mx, __shfl_xor(mx, off));
        const float mnew = fmaxf(m, mx);
        const float scale = __expf(m - mnew);
        const float e = (n < cact) ? __expf(s - mnew) : 0.f;
        float se = e;                           // quad-uniform: butterfly sums each nbr once
        #pragma unroll
        for (int off = 4; off < 64; off <<= 1) se += __shfl_xor(se, off);
        l = l * scale + se;
        m = mnew;
        accA *= scale; accB *= scale;
        if (q == 0) wS[k][n] = e;               // e = 0 for n >= cact
        __syncthreads();                        // RAW fence: stage/wS writes -> agg reads
        // --- aggregation from LDS: half-wave on c-parity, 2 dims/lane (u32) ---
        for (int c = half; c < cact; c += 2) {
            const float wgt = wS[k][c];         // 2 distinct addrs/wave: broadcast
            u32 z2 = zbufU[k][c][L];
            accA += wgt * bflo(z2);
            accB += wgt * bfhi(z2);
        }
        __syncthreads();                        // WAR fence: agg reads -> next chunk's writes
    }
    accA += __shfl_xor(accA, 32);               // combine even/odd-c halves
    accB += __shfl_xor(accB, 32);
    if (lane < 32) {
        const float inv = 1.0f / l;
        u32 o = ((u32)f2bf(accA * inv)) | (((u32)f2bf(accB * inv)) << 16);
        *(u32*)(Zaggb + (size_t)i * DD + k * 64 + 2 * L) = o;
    }
}

// ---------------------------------------------------------------------------
// K3: out = relu(H + 0.5 * (Zaggb . Bt2^T) - thr), f32 out. 64x64, BK=64.
// ---------------------------------------------------------------------------
__global__ __launch_bounds__(256) void outgemm_mfma(const u16* __restrict__ Ab, const u16* __restrict__ Btb,
                                                    const float* __restrict__ H, const float* __restrict__ thr,
                                                    float* __restrict__ out) {
    __shared__ short As[64][72];
    __shared__ short Bs[64][72];
    const int t = threadIdx.x;
    const int i0 = blockIdx.x * 64, n0 = blockIdx.y * 64;
    const int w = t >> 6, lane = t & 63;
    const int lm = lane & 15, lg = lane >> 4;
    f32x4 acc[4] = {};
    for (int kc = 0; kc < DD; kc += 64) {
        #pragma unroll
        for (int s = 0; s < 2; s++) {
            int c = t + 256 * s; int row = c >> 3, g = c & 7;
            *(short8*)&As[row][g * 8] = *(const short8*)(Ab  + (size_t)(i0 + row) * DD + kc + g * 8);
            *(short8*)&Bs[row][g * 8] = *(const short8*)(Btb + (size_t)(n0 + row) * DD + kc + g * 8);
        }
        __syncthreads();
        #pragma unroll
        for (int ks = 0; ks < 64; ks += 32) {
            short8 af = *(const short8*)&As[w * 16 + lm][ks + lg * 8];
            #pragma unroll
            for (int b = 0; b < 4; b++) {
                short8 bfr = *(const short8*)&Bs[b * 16 + lm][ks + lg * 8];
                acc[b] = __builtin_amdgcn_mfma_f32_16x16x32_bf16(af, bfr, acc[b], 0, 0, 0);
            }
        }
        __syncthreads();
    }
    #pragma unroll
    for (int b = 0; b < 4; b++) {
        const int col = n0 + b * 16 + lm;
        const float th = thr[col];
        #pragma unroll
        for (int q = 0; q < 4; q++) {
            int row = i0 + w * 16 + lg * 4 + q;
            float h = H[(size_t)row * DD + col];
            out[(size_t)row * DD + col] = fmaxf(h + 0.5f * acc[b][q] - th, 0.f);
        }
    }
}

// ---------------------------------------------------------------------------
// K4: orth loss, LDS-staged; last block writes loss to out[NN*DD].
// ---------------------------------------------------------------------------
__global__ __launch_bounds__(256) void orth_kernel(const float* __restrict__ U, float* __restrict__ loss,
                                                   int* __restrict__ done, float* __restrict__ outLoss) {
    __shared__ float UkT[64][20];   // [dd][r_local]
    __shared__ float UlT[64][68];   // [dd][s]
    const int pb = blockIdx.x >> 2, strip = blockIdx.x & 3;
    int idx = pb, k = 0, lh = 1;
    #pragma unroll
    for (int kk = 0; kk < 8; kk++) {
        int c = 7 - kk;
        if (idx < c) { k = kk; lh = kk + 1 + idx; break; }
        idx -= c;
    }
    const int t = threadIdx.x;
    const int r = t & 15;
    const int s0 = (t >> 4) * 4;
    const int r0g = strip * 16;
    const float* Uk = U + (size_t)k  * DD * RR;
    const float* Ul = U + (size_t)lh * DD * RR;
    float a0 = 0.f, a1 = 0.f, a2 = 0.f, a3 = 0.f;
    for (int dc = 0; dc < DD; dc += 64) {
        {   int dd = t >> 2, rq = t & 3;
            *(float4*)&UkT[dd][rq * 4] = *(const float4*)(Uk + (size_t)(dc + dd) * RR + r0g + rq * 4);
        }
        #pragma unroll
        for (int s = 0; s < 4; s++) {
            int u = t + 256 * s;
            int dd = u >> 4, sq = u & 15;
            *(float4*)&UlT[dd][sq * 4] = *(const float4*)(Ul + (size_t)(dc + dd) * RR + sq * 4);
        }
        __syncthreads();
        #pragma unroll 4
        for (int dd = 0; dd < 64; dd++) {
            float a = UkT[dd][r];
            float4 bv = *(const float4*)&UlT[dd][s0];
            a0 += a * bv.x; a1 += a * bv.y; a2 += a * bv.z; a3 += a * bv.w;
        }
        __syncthreads();
    }
    float v = a0 * a0 + a1 * a1 + a2 * a2 + a3 * a3;
    #pragma unroll
    for (int off = 32; off; off >>= 1) v += __shfl_down(v, off, 64);
    __shared__ float red[4];
    if ((t & 63) == 0) red[t >> 6] = v;
    __syncthreads();
    if (t == 0) {
        atomicAdd(loss, red[0] + red[1] + red[2] + red[3]);
        __threadfence();
        int d = atomicAdd(done, 1);
        if (d == 111) {
            float total = atomicAdd(loss, 0.f);   // device-coherent read of final sum
            outLoss[0] = total;
        }
    }
}

// ---------------------------------------------------------------------------
extern "C" void kernel_launch(void* const* d_in, const int* in_sizes, int n_in,
                              void* d_out, int out_size, void* d_ws, size_t ws_size,
                              hipStream_t stream) {
    const float* H   = (const float*)d_in[0];
    const float* adj = (const float*)d_in[1];
    const float* U   = (const float*)d_in[2];
    const float* thr = (const float*)d_in[3];
    float* out = (float*)d_out;

    char* ws = (char*)d_ws;
    float* lossA = (float*)ws;                                         // 4 B
    int*   doneA = (int*)(ws + 64);                                    // 4 B
    u16*   Hb    = (u16*)(ws + 1024);                                  // 4 MB
    u16*   Zb    = (u16*)(ws + 1024 + 4u * 1024 * 1024);               // 4 MB
    u16*   Zaggb = (u16*)(ws + 1024 + 8u * 1024 * 1024);               // 4 MB
    u16*   Bt1   = (u16*)(ws + 1024 + 12u * 1024 * 1024);              // 512 KB
    u16*   Bt2   = (u16*)(ws + 1024 + 12u * 1024 * 1024 + 512u * 1024);// 512 KB
    int*   nlist = (int*)(ws + 1024 + 13u * 1024 * 1024);              // 2 MB
    int*   cnt   = (int*)(ws + 1024 + 15u * 1024 * 1024 + 512u * 1024);// 16 KB

    prep_scan<<<6209, 256, 0, stream>>>(H, U, adj, Hb, Bt1, Bt2, nlist, cnt, lossA, doneA);
    zgemm_mfma<<<dim3(64, 8), 256, 0, stream>>>(Hb, Bt1, Zb);
    attn7<<<NN, 512, 0, stream>>>(Zb, nlist, cnt, Zaggb);
    outgemm_mfma<<<dim3(64, 8), 256, 0, stream>>>(Zaggb, Bt2, H, thr, out);
    orth_kernel<<<112, 256, 0, stream>>>(U, lossA, doneA, out + (size_t)NN * DD);
}